// Round 10
// baseline (477.252 us; speedup 1.0000x reference)
//
#include <hip/hip_runtime.h>
#include <hip/hip_bf16.h>

#define DD 128

typedef __attribute__((ext_vector_type(8))) short short8;
typedef __attribute__((ext_vector_type(4))) float f32x4;

static __device__ __forceinline__ int gtid() {
    return blockIdx.x * blockDim.x + threadIdx.x;
}

static __device__ __forceinline__ ushort f2bfu(float f) {
    __hip_bfloat16 h = __float2bfloat16(f);
    return *reinterpret_cast<ushort*>(&h);
}

// ---- fp8 e4m3fn encode (manual fallback, RNE, subnormal-correct) ----
static __device__ __forceinline__ unsigned int fp8e(float f) {
    unsigned int s = (__float_as_uint(f) >> 31) << 7;
    float a = fabsf(f);
    if (a < 0.015625f) return s | (unsigned int)rintf(a * 512.0f);  // subnormal
    unsigned int u = __float_as_uint(a);
    u += 0x0007FFFFu + ((u >> 20) & 1u);           // RNE round mantissa to 3 bits
    unsigned int e8 = (u >> 23) - 120u;
    unsigned int m = (u >> 20) & 7u;
    if (e8 > 15u || (e8 == 15u && m == 7u)) return s | 0x7Eu;  // clamp to 448
    return s | (e8 << 3) | m;
}

// pack 4 f32 -> 4 fp8 bytes (HW cvt when available)
static __device__ __forceinline__ unsigned int pk8x4(float a, float b, float c, float d) {
#if __has_builtin(__builtin_amdgcn_cvt_pk_fp8_f32)
    int v = __builtin_amdgcn_cvt_pk_fp8_f32(a, b, 0, false);
    v = __builtin_amdgcn_cvt_pk_fp8_f32(c, d, v, true);
    return (unsigned int)v;
#else
    return fp8e(a) | (fp8e(b) << 8) | (fp8e(c) << 16) | (fp8e(d) << 24);
#endif
}

// ---------- degree / CSR build ----------

__global__ void count_kernel(int* __restrict__ counts, const int* __restrict__ dst, int e) {
    int i = gtid();
    if (i < e) atomicAdd(&counts[dst[i]], 1);
}

__global__ void dinv_kernel(float* __restrict__ dinv, const int* __restrict__ counts, int n) {
    int i = gtid();
    if (i < n) dinv[i] = rsqrtf(1.0f + (float)counts[i]);
}

__global__ __launch_bounds__(256) void scan_blocks(const int* __restrict__ counts,
                                                   int* __restrict__ rowptr,
                                                   int* __restrict__ partial, int n) {
    __shared__ int s[256];
    int i = blockIdx.x * 256 + threadIdx.x;
    int v = (i < n) ? counts[i] : 0;
    s[threadIdx.x] = v;
    __syncthreads();
    for (int off = 1; off < 256; off <<= 1) {
        int t = (threadIdx.x >= off) ? s[threadIdx.x - off] : 0;
        __syncthreads();
        s[threadIdx.x] += t;
        __syncthreads();
    }
    if (i < n) rowptr[i] = s[threadIdx.x] - v;
    if (threadIdx.x == 255) partial[blockIdx.x] = s[255];
}

__global__ __launch_bounds__(256) void scan_partials(int* __restrict__ partial,
                                                     int* __restrict__ partial2, int nb) {
    __shared__ int s[256];
    int v = (threadIdx.x < nb) ? partial[threadIdx.x] : 0;
    s[threadIdx.x] = v;
    __syncthreads();
    for (int off = 1; off < 256; off <<= 1) {
        int t = (threadIdx.x >= off) ? s[threadIdx.x - off] : 0;
        __syncthreads();
        s[threadIdx.x] += t;
        __syncthreads();
    }
    partial2[threadIdx.x] = s[threadIdx.x] - v;
}

__global__ __launch_bounds__(256) void add_offsets(int* __restrict__ rowptr,
                                                   int* __restrict__ cursor,
                                                   const int* __restrict__ partial2,
                                                   int n, int e) {
    int i = blockIdx.x * 256 + threadIdx.x;
    if (i < n) {
        int r = rowptr[i] + partial2[blockIdx.x];
        rowptr[i] = r;
        cursor[i] = r;
        if (i == n - 1) rowptr[n] = e;
    }
}

__global__ void fill_kernel(const int* __restrict__ ei, const float* __restrict__ dinv,
                            int* __restrict__ cursor, int* __restrict__ csr_src,
                            float* __restrict__ csr_coef, int e) {
    int i = gtid();
    if (i >= e) return;
    int s = ei[i];
    int d = ei[e + i];
    float c = dinv[s] * dinv[d];
    int pos = atomicAdd(&cursor[d], 1);
    csr_src[pos] = s;
    csr_coef[pos] = c;
}

// ---------- x -> bf16 ----------
__global__ void cvt_kernel(const float* __restrict__ x, __hip_bfloat16* __restrict__ xh, size_t m) {
    size_t i = (size_t)blockIdx.x * blockDim.x + threadIdx.x;
    if (i < m) xh[i] = __float2bfloat16(x[i]);
}

// ---------- W -> bf16 MFMA B-fragment order ----------
__global__ __launch_bounds__(256) void wpack_kernel(const float* __restrict__ gcn_w,
                                                    ushort* __restrict__ wfrag) {
    int tid = blockIdx.x * 256 + threadIdx.x;
    if (tid >= 3 * 4 * 8 * 64) return;
    int lane = tid & 63;
    int c = (tid >> 6) & 7;
    int s = (tid >> 9) & 3;
    int l = tid >> 11;
    const float* W = gcn_w + (size_t)l * 128 * 128;
    int col = c * 16 + (lane & 15);
    int k0 = s * 32 + (lane >> 4) * 8;
    ushort u[8];
#pragma unroll
    for (int j = 0; j < 8; ++j) {
        u[j] = f2bfu(W[(size_t)(k0 + j) * 128 + col]);
    }
    *reinterpret_cast<uint4*>(wfrag + (size_t)tid * 8) = *reinterpret_cast<const uint4*>(u);
}

// ---------- MFMA GEMM ----------
__global__ __launch_bounds__(256) void gemm_mfma_kernel(
    const ushort* __restrict__ hsrc, int ld, const ushort* __restrict__ wfrag,
    ushort* __restrict__ out, int ntiles) {
    int lane = threadIdx.x & 63;
    int wv = threadIdx.x >> 6;
    short8 b0[4], b1[4];
    int c0 = wv * 2;
#pragma unroll
    for (int s = 0; s < 4; ++s) {
        b0[s] = *reinterpret_cast<const short8*>(wfrag + ((size_t)(s * 8 + c0) * 64 + lane) * 8);
        b1[s] = *reinterpret_cast<const short8*>(wfrag + ((size_t)(s * 8 + c0 + 1) * 64 + lane) * 8);
    }
    int rlo = lane & 15;
    int kg = lane >> 4;
    for (int rt = blockIdx.x; rt < ntiles; rt += gridDim.x) {
        const ushort* ap = hsrc + (size_t)(rt * 16 + rlo) * ld + kg * 8;
        short8 a0 = *reinterpret_cast<const short8*>(ap);
        short8 a1 = *reinterpret_cast<const short8*>(ap + 32);
        short8 a2 = *reinterpret_cast<const short8*>(ap + 64);
        short8 a3 = *reinterpret_cast<const short8*>(ap + 96);
        f32x4 acc0 = {0.f, 0.f, 0.f, 0.f};
        f32x4 acc1 = {0.f, 0.f, 0.f, 0.f};
        acc0 = __builtin_amdgcn_mfma_f32_16x16x32_bf16(a0, b0[0], acc0, 0, 0, 0);
        acc1 = __builtin_amdgcn_mfma_f32_16x16x32_bf16(a0, b1[0], acc1, 0, 0, 0);
        acc0 = __builtin_amdgcn_mfma_f32_16x16x32_bf16(a1, b0[1], acc0, 0, 0, 0);
        acc1 = __builtin_amdgcn_mfma_f32_16x16x32_bf16(a1, b1[1], acc1, 0, 0, 0);
        acc0 = __builtin_amdgcn_mfma_f32_16x16x32_bf16(a2, b0[2], acc0, 0, 0, 0);
        acc1 = __builtin_amdgcn_mfma_f32_16x16x32_bf16(a2, b1[2], acc1, 0, 0, 0);
        acc0 = __builtin_amdgcn_mfma_f32_16x16x32_bf16(a3, b0[3], acc0, 0, 0, 0);
        acc1 = __builtin_amdgcn_mfma_f32_16x16x32_bf16(a3, b1[3], acc1, 0, 0, 0);
        int row0 = rt * 16 + kg * 4;
        ushort* orow = out + (size_t)row0 * 128 + wv * 32 + rlo;
#pragma unroll
        for (int r = 0; r < 4; ++r) {
            orow[(size_t)r * 128] = f2bfu(acc0[r]);
            orow[(size_t)r * 128 + 16] = f2bfu(acc1[r]);
        }
    }
}

// ---------- column-split fused aggregate: 32 features per pass ----------
// One wave per dst row per pass. Lane layout: g = lane>>2 (16 edge slots),
// c = lane&3 (4x 8-feature chunks = 32 feats). Each edge gather = exactly one
// 64B cache line (4 lanes x 16B). Per-pass gather footprint = n x 64B = 3.2MB
// -> fits per-XCD 4MB L2.
__global__ __launch_bounds__(256) void aggregate_pass_kernel(
    const ushort* __restrict__ hw, const int* __restrict__ rowptr,
    const int* __restrict__ csr_src, const float* __restrict__ csr_coef,
    const float* __restrict__ dinv, const float* __restrict__ bias,
    const float* __restrict__ pwsl,
    ushort* __restrict__ zsl, unsigned char* __restrict__ zqsl,
    unsigned char* __restrict__ zqwsl, int n, int colOff) {
    int gid = gtid();
    int row = gid >> 6;
    if (row >= n) return;
    int lane = threadIdx.x & 63;
    int g = lane >> 2;   // edge slot 0..15
    int c = lane & 3;    // feature chunk (8 feats)
    int j0 = rowptr[row], j1 = rowptr[row + 1];
    float acc[8] = {0.f, 0.f, 0.f, 0.f, 0.f, 0.f, 0.f, 0.f};
    for (int j = j0 + g; j < j1; j += 16) {
        int s = csr_src[j];
        float cf = csr_coef[j];
        uint4 v = *reinterpret_cast<const uint4*>(hw + (size_t)s * 128 + colOff + c * 8);
        const unsigned int* u = (const unsigned int*)&v;
#pragma unroll
        for (int q = 0; q < 4; ++q) {
            acc[2 * q] = fmaf(cf, __uint_as_float(u[q] << 16), acc[2 * q]);
            acc[2 * q + 1] = fmaf(cf, __uint_as_float(u[q] & 0xffff0000u), acc[2 * q + 1]);
        }
    }
    // reduce across the 16 edge slots
#pragma unroll
    for (int k = 0; k < 8; ++k) {
        acc[k] += __shfl_xor(acc[k], 4);
        acc[k] += __shfl_xor(acc[k], 8);
        acc[k] += __shfl_xor(acc[k], 16);
        acc[k] += __shfl_xor(acc[k], 32);
    }
    // self-loop + bias + relu (all lanes hold full reduced chunk c)
    float di = dinv[row];
    float d2 = di * di;
    uint4 sv = *reinterpret_cast<const uint4*>(hw + (size_t)row * 128 + colOff + c * 8);
    const unsigned int* su = (const unsigned int*)&sv;
    float4 bv0 = *reinterpret_cast<const float4*>(bias + colOff + c * 8);
    float4 bv1 = *reinterpret_cast<const float4*>(bias + colOff + c * 8 + 4);
    const float* bp0 = (const float*)&bv0;
    const float* bp1 = (const float*)&bv1;
#pragma unroll
    for (int q = 0; q < 4; ++q) {
        float f0 = __uint_as_float(su[q] << 16);
        float f1 = __uint_as_float(su[q] & 0xffff0000u);
        float b0 = (q < 2) ? bp0[2 * q] : bp1[2 * (q - 2)];
        float b1 = (q < 2) ? bp0[2 * q + 1] : bp1[2 * (q - 2) + 1];
        acc[2 * q] = fmaf(d2, f0, acc[2 * q]) + b0;
        acc[2 * q + 1] = fmaf(d2, f1, acc[2 * q + 1]) + b1;
    }
#pragma unroll
    for (int k = 0; k < 8; ++k) acc[k] = fmaxf(acc[k], 0.f);

    if (g == 0) {
        // bf16 store: 4 lanes x 16B = contiguous 64B slice of the row
        unsigned int pk[4];
#pragma unroll
        for (int q = 0; q < 4; ++q) {
            pk[q] = (unsigned int)f2bfu(acc[2 * q]) | ((unsigned int)f2bfu(acc[2 * q + 1]) << 16);
        }
        *reinterpret_cast<uint4*>(zsl + (size_t)row * 384 + colOff + c * 8) =
            *reinterpret_cast<const uint4*>(pk);
    } else if (g == 1) {
        uint2 qq;
        qq.x = pk8x4(acc[0], acc[1], acc[2], acc[3]);
        qq.y = pk8x4(acc[4], acc[5], acc[6], acc[7]);
        *reinterpret_cast<uint2*>(zqsl + (size_t)row * 384 + colOff + c * 8) = qq;
    } else if (g == 2) {
        float4 pv0 = *reinterpret_cast<const float4*>(pwsl + colOff + c * 8);
        float4 pv1 = *reinterpret_cast<const float4*>(pwsl + colOff + c * 8 + 4);
        const float* pp0 = (const float*)&pv0;
        const float* pp1 = (const float*)&pv1;
        uint2 ww;
        ww.x = pk8x4(acc[0] * pp0[0] * 8.0f, acc[1] * pp0[1] * 8.0f,
                     acc[2] * pp0[2] * 8.0f, acc[3] * pp0[3] * 8.0f);
        ww.y = pk8x4(acc[4] * pp1[0] * 8.0f, acc[5] * pp1[1] * 8.0f,
                     acc[6] * pp1[2] * 8.0f, acc[7] * pp1[3] * 8.0f);
        *reinterpret_cast<uint2*>(zqwsl + (size_t)row * 384 + colOff + c * 8) = ww;
    }
}

// ---------- loss: fp8 MFMA diagonal dot; 16 pairs per wave; partial per block ----------
__global__ __launch_bounds__(256) void loss_mfma_kernel(
    const unsigned char* __restrict__ zq, const unsigned char* __restrict__ zqw,
    const int* __restrict__ pos, const int* __restrict__ neg,
    const float* __restrict__ pb, float* __restrict__ partialOut,
    int p, float inv_total) {
    __shared__ float red[4];
    int lane = threadIdx.x & 63;
    int wv = threadIdx.x >> 6;
    int pairBase = (blockIdx.x * 4 + wv) * 16;
    float term = 0.f;
    if (pairBase < 2 * p) {
        int m = lane & 15;   // pair within wave
        int kg = lane >> 4;  // k-octet
        int pi = pairBase + m;
        int pic = (pi < 2 * p) ? pi : (2 * p - 1);
        bool isneg = (pic >= p);
        const int* pr = isneg ? neg : pos;
        int idx = isneg ? (pic - p) : pic;
        int a = pr[idx];
        int b = pr[p + idx];
        const long* pa = reinterpret_cast<const long*>(zq + (size_t)a * 384) + kg;
        const long* pbw = reinterpret_cast<const long*>(zqw + (size_t)b * 384) + kg;
        long av[12], bv[12];
#pragma unroll
        for (int s = 0; s < 12; ++s) av[s] = pa[s * 4];
#pragma unroll
        for (int s = 0; s < 12; ++s) bv[s] = pbw[s * 4];
        f32x4 acc = {0.f, 0.f, 0.f, 0.f};
#pragma unroll
        for (int s = 0; s < 12; ++s) {
            acc = __builtin_amdgcn_mfma_f32_16x16x32_fp8_fp8(av[s], bv[s], acc, 0, 0, 0);
        }
        bool isdiag = (lane >> 4) == ((lane & 15) >> 2);
        int r2 = lane & 3;
        float v = (r2 == 0) ? acc[0] : (r2 == 1) ? acc[1] : (r2 == 2) ? acc[2] : acc[3];
        if (isdiag && pi < 2 * p) {
            float logit = v * 0.125f + pb[0];
            float t = isneg ? logit : -logit;  // softplus argument
            term = (fmaxf(t, 0.f) + log1pf(expf(-fabsf(t)))) * inv_total;
        }
    }
#pragma unroll
    for (int off = 1; off < 64; off <<= 1) term += __shfl_xor(term, off);
    if (lane == 0) red[wv] = term;
    __syncthreads();
    if (threadIdx.x == 0) partialOut[blockIdx.x] = red[0] + red[1] + red[2] + red[3];
}

// single-block final reduction (no atomics)
__global__ __launch_bounds__(256) void loss_reduce_kernel(
    const float* __restrict__ partial, float* __restrict__ out, int m) {
    __shared__ float s[256];
    float a = 0.f;
    for (int i = threadIdx.x; i < m; i += 256) a += partial[i];
    s[threadIdx.x] = a;
    __syncthreads();
    for (int off = 128; off > 0; off >>= 1) {
        if (threadIdx.x < off) s[threadIdx.x] += s[threadIdx.x + off];
        __syncthreads();
    }
    if (threadIdx.x == 0) out[0] = s[0];
}

extern "C" void kernel_launch(void* const* d_in, const int* in_sizes, int n_in,
                              void* d_out, int out_size, void* d_ws, size_t ws_size,
                              hipStream_t stream) {
    const float* x      = (const float*)d_in[0];
    const int*   ei     = (const int*)d_in[1];
    const int*   pos    = (const int*)d_in[2];
    const int*   neg    = (const int*)d_in[3];
    const float* gcn_w  = (const float*)d_in[4];
    const float* gcn_b  = (const float*)d_in[5];
    const float* pred_w = (const float*)d_in[6];
    const float* pred_b = (const float*)d_in[7];
    float* out = (float*)d_out;

    const int n = in_sizes[0] / DD;     // 50000
    const int e = in_sizes[1] / 2;      // 640000
    const int p = in_sizes[2] / 2;      // 100000
    const int nb = (n + 255) / 256;

    char* ws = (char*)d_ws;
    size_t off = 0;
    auto alloc = [&](size_t bytes) {
        void* ptr = ws + off;
        off += (bytes + 255) & ~(size_t)255;
        return ptr;
    };
    float* dinv      = (float*)alloc((size_t)n * 4);
    int*   counts    = (int*)alloc((size_t)n * 4);
    int*   rowptr    = (int*)alloc((size_t)(n + 1) * 4);
    int*   cursor    = (int*)alloc((size_t)n * 4);
    int*   partial   = (int*)alloc(256 * 4);
    int*   partial2  = (int*)alloc(256 * 4);
    float* lossPart  = (float*)alloc((size_t)4096 * 4);
    int*   csr_src   = (int*)alloc((size_t)e * 4);
    float* csr_coef  = (float*)alloc((size_t)e * 4);
    ushort* wfrag    = (ushort*)alloc((size_t)3 * 2048 * 8 * 2);
    ushort* xh = (ushort*)alloc((size_t)n * 128 * 2);
    ushort* hw = (ushort*)alloc((size_t)n * 128 * 2);
    ushort* zh = (ushort*)alloc((size_t)n * 384 * 2);
    unsigned char* zq  = (unsigned char*)alloc((size_t)n * 384);
    unsigned char* zqw = (unsigned char*)alloc((size_t)n * 384);
    (void)ws_size;

    hipMemsetAsync(counts, 0, (size_t)n * 4, stream);
    hipMemsetAsync(d_out, 0, (size_t)out_size * 4, stream);

    count_kernel<<<(e + 255) / 256, 256, 0, stream>>>(counts, ei + e, e);
    dinv_kernel<<<nb, 256, 0, stream>>>(dinv, counts, n);
    scan_blocks<<<nb, 256, 0, stream>>>(counts, rowptr, partial, n);
    scan_partials<<<1, 256, 0, stream>>>(partial, partial2, nb);
    add_offsets<<<nb, 256, 0, stream>>>(rowptr, cursor, partial2, n, e);
    fill_kernel<<<(e + 255) / 256, 256, 0, stream>>>(ei, dinv, cursor, csr_src, csr_coef, e);

    cvt_kernel<<<(int)(((size_t)n * 128 + 255) / 256), 256, 0, stream>>>(
        x, (__hip_bfloat16*)xh, (size_t)n * 128);
    wpack_kernel<<<24, 256, 0, stream>>>(gcn_w, wfrag);

    const int ntiles = n / 16;
    const int aggBlocks = (n * 64 + 255) / 256;
    for (int l = 0; l < 3; ++l) {
        const ushort* hsrc = (l == 0) ? xh : (zh + (size_t)(l - 1) * 128);
        int ld = (l == 0) ? 128 : 384;
        gemm_mfma_kernel<<<ntiles, 256, 0, stream>>>(
            hsrc, ld, wfrag + (size_t)l * 2048 * 8, hw, ntiles);
        for (int pass = 0; pass < 4; ++pass) {
            aggregate_pass_kernel<<<aggBlocks, 256, 0, stream>>>(
                hw, rowptr, csr_src, csr_coef, dinv, gcn_b + (size_t)l * 128,
                pred_w + (size_t)l * 128,
                zh + (size_t)l * 128, zq + (size_t)l * 128, zqw + (size_t)l * 128,
                n, pass * 32);
        }
    }

    float inv_total = 1.0f / (2.0f * (float)p);
    int lossBlocks = (2 * p + 63) / 64;  // 3125
    loss_mfma_kernel<<<lossBlocks, 256, 0, stream>>>(
        zq, zqw, pos, neg, pred_b, lossPart, p, inv_total);
    loss_reduce_kernel<<<1, 256, 0, stream>>>(lossPart, out, lossBlocks);
}

// Round 11
// 288.185 us; speedup vs baseline: 1.6561x; 1.6561x over previous
//
#include <hip/hip_runtime.h>
#include <hip/hip_bf16.h>

#define DD 128

typedef __attribute__((ext_vector_type(8))) short short8;
typedef __attribute__((ext_vector_type(4))) float f32x4;
typedef __attribute__((ext_vector_type(2))) float f32x2;

static __device__ __forceinline__ int gtid() {
    return blockIdx.x * blockDim.x + threadIdx.x;
}

static __device__ __forceinline__ ushort f2bfu(float f) {
    __hip_bfloat16 h = __float2bfloat16(f);
    return *reinterpret_cast<ushort*>(&h);
}

// ---- fp8 e4m3fn encode/decode (manual fallback, RNE, subnormal-correct) ----
static __device__ __forceinline__ unsigned int fp8e(float f) {
    unsigned int s = (__float_as_uint(f) >> 31) << 7;
    float a = fabsf(f);
    if (a < 0.015625f) return s | (unsigned int)rintf(a * 512.0f);
    unsigned int u = __float_as_uint(a);
    u += 0x0007FFFFu + ((u >> 20) & 1u);
    unsigned int e8 = (u >> 23) - 120u;
    unsigned int m = (u >> 20) & 7u;
    if (e8 > 15u || (e8 == 15u && m == 7u)) return s | 0x7Eu;
    return s | (e8 << 3) | m;
}

static __device__ __forceinline__ float fp8d(unsigned int b) {
    unsigned int t = b & 0x7Fu;
    float v = (t >= 8u) ? __uint_as_float((t << 20) + 0x3C000000u)
                        : (float)t * 0.001953125f;
    return (b & 0x80u) ? -v : v;
}

// pack 4 f32 -> 4 fp8 bytes
static __device__ __forceinline__ unsigned int pk8x4(float a, float b, float c, float d) {
#if __has_builtin(__builtin_amdgcn_cvt_pk_fp8_f32)
    int v = __builtin_amdgcn_cvt_pk_fp8_f32(a, b, 0, false);
    v = __builtin_amdgcn_cvt_pk_fp8_f32(c, d, v, true);
    return (unsigned int)v;
#else
    return fp8e(a) | (fp8e(b) << 8) | (fp8e(c) << 16) | (fp8e(d) << 24);
#endif
}

// pack 2 f32 -> 2 fp8 bytes (low word)
static __device__ __forceinline__ unsigned int pk8x2(float a, float b) {
#if __has_builtin(__builtin_amdgcn_cvt_pk_fp8_f32)
    return (unsigned int)__builtin_amdgcn_cvt_pk_fp8_f32(a, b, 0, false);
#else
    return fp8e(a) | (fp8e(b) << 8);
#endif
}

// decode 4 fp8 bytes -> 4 f32
static __device__ __forceinline__ void fp8x4_dec(unsigned int u, float* f) {
#if __has_builtin(__builtin_amdgcn_cvt_pk_f32_fp8)
    f32x2 lo = __builtin_amdgcn_cvt_pk_f32_fp8((int)u, false);
    f32x2 hi = __builtin_amdgcn_cvt_pk_f32_fp8((int)u, true);
    f[0] = lo[0]; f[1] = lo[1]; f[2] = hi[0]; f[3] = hi[1];
#else
    f[0] = fp8d(u & 0xFFu);
    f[1] = fp8d((u >> 8) & 0xFFu);
    f[2] = fp8d((u >> 16) & 0xFFu);
    f[3] = fp8d((u >> 24) & 0xFFu);
#endif
}

// ---------- degree / CSR build ----------

__global__ void count_kernel(int* __restrict__ counts, const int* __restrict__ dst, int e) {
    int i = gtid();
    if (i < e) atomicAdd(&counts[dst[i]], 1);
}

__global__ void dinv_kernel(float* __restrict__ dinv, const int* __restrict__ counts, int n) {
    int i = gtid();
    if (i < n) dinv[i] = rsqrtf(1.0f + (float)counts[i]);
}

__global__ __launch_bounds__(256) void scan_blocks(const int* __restrict__ counts,
                                                   int* __restrict__ rowptr,
                                                   int* __restrict__ partial, int n) {
    __shared__ int s[256];
    int i = blockIdx.x * 256 + threadIdx.x;
    int v = (i < n) ? counts[i] : 0;
    s[threadIdx.x] = v;
    __syncthreads();
    for (int off = 1; off < 256; off <<= 1) {
        int t = (threadIdx.x >= off) ? s[threadIdx.x - off] : 0;
        __syncthreads();
        s[threadIdx.x] += t;
        __syncthreads();
    }
    if (i < n) rowptr[i] = s[threadIdx.x] - v;
    if (threadIdx.x == 255) partial[blockIdx.x] = s[255];
}

__global__ __launch_bounds__(256) void scan_partials(int* __restrict__ partial,
                                                     int* __restrict__ partial2, int nb) {
    __shared__ int s[256];
    int v = (threadIdx.x < nb) ? partial[threadIdx.x] : 0;
    s[threadIdx.x] = v;
    __syncthreads();
    for (int off = 1; off < 256; off <<= 1) {
        int t = (threadIdx.x >= off) ? s[threadIdx.x - off] : 0;
        __syncthreads();
        s[threadIdx.x] += t;
        __syncthreads();
    }
    partial2[threadIdx.x] = s[threadIdx.x] - v;
}

__global__ __launch_bounds__(256) void add_offsets(int* __restrict__ rowptr,
                                                   int* __restrict__ cursor,
                                                   const int* __restrict__ partial2,
                                                   int n, int e) {
    int i = blockIdx.x * 256 + threadIdx.x;
    if (i < n) {
        int r = rowptr[i] + partial2[blockIdx.x];
        rowptr[i] = r;
        cursor[i] = r;
        if (i == n - 1) rowptr[n] = e;
    }
}

// src-only fill (coef computed on the fly in aggregate)
__global__ void fill_kernel(const int* __restrict__ ei, int* __restrict__ cursor,
                            int* __restrict__ csr_src, int e) {
    int i = gtid();
    if (i >= e) return;
    int s = ei[i];
    int d = ei[e + i];
    int pos = atomicAdd(&cursor[d], 1);
    csr_src[pos] = s;
}

// ---------- x -> bf16 ----------
__global__ void cvt_kernel(const float* __restrict__ x, __hip_bfloat16* __restrict__ xh, size_t m) {
    size_t i = (size_t)blockIdx.x * blockDim.x + threadIdx.x;
    if (i < m) xh[i] = __float2bfloat16(x[i]);
}

// ---------- W -> bf16 MFMA B-fragment order ----------
__global__ __launch_bounds__(256) void wpack_kernel(const float* __restrict__ gcn_w,
                                                    ushort* __restrict__ wfrag) {
    int tid = blockIdx.x * 256 + threadIdx.x;
    if (tid >= 3 * 4 * 8 * 64) return;
    int lane = tid & 63;
    int c = (tid >> 6) & 7;
    int s = (tid >> 9) & 3;
    int l = tid >> 11;
    const float* W = gcn_w + (size_t)l * 128 * 128;
    int col = c * 16 + (lane & 15);
    int k0 = s * 32 + (lane >> 4) * 8;
    ushort u[8];
#pragma unroll
    for (int j = 0; j < 8; ++j) {
        u[j] = f2bfu(W[(size_t)(k0 + j) * 128 + col]);
    }
    *reinterpret_cast<uint4*>(wfrag + (size_t)tid * 8) = *reinterpret_cast<const uint4*>(u);
}

// ---------- MFMA GEMM: bf16 in, fp8 out ----------
__global__ __launch_bounds__(256) void gemm_mfma_kernel(
    const ushort* __restrict__ hsrc, int ld, const ushort* __restrict__ wfrag,
    unsigned char* __restrict__ outq, int ntiles) {
    int lane = threadIdx.x & 63;
    int wv = threadIdx.x >> 6;
    short8 b0[4], b1[4];
    int c0 = wv * 2;
#pragma unroll
    for (int s = 0; s < 4; ++s) {
        b0[s] = *reinterpret_cast<const short8*>(wfrag + ((size_t)(s * 8 + c0) * 64 + lane) * 8);
        b1[s] = *reinterpret_cast<const short8*>(wfrag + ((size_t)(s * 8 + c0 + 1) * 64 + lane) * 8);
    }
    int rlo = lane & 15;
    int kg = lane >> 4;
    for (int rt = blockIdx.x; rt < ntiles; rt += gridDim.x) {
        const ushort* ap = hsrc + (size_t)(rt * 16 + rlo) * ld + kg * 8;
        short8 a0 = *reinterpret_cast<const short8*>(ap);
        short8 a1 = *reinterpret_cast<const short8*>(ap + 32);
        short8 a2 = *reinterpret_cast<const short8*>(ap + 64);
        short8 a3 = *reinterpret_cast<const short8*>(ap + 96);
        f32x4 acc0 = {0.f, 0.f, 0.f, 0.f};
        f32x4 acc1 = {0.f, 0.f, 0.f, 0.f};
        acc0 = __builtin_amdgcn_mfma_f32_16x16x32_bf16(a0, b0[0], acc0, 0, 0, 0);
        acc1 = __builtin_amdgcn_mfma_f32_16x16x32_bf16(a0, b1[0], acc1, 0, 0, 0);
        acc0 = __builtin_amdgcn_mfma_f32_16x16x32_bf16(a1, b0[1], acc0, 0, 0, 0);
        acc1 = __builtin_amdgcn_mfma_f32_16x16x32_bf16(a1, b1[1], acc1, 0, 0, 0);
        acc0 = __builtin_amdgcn_mfma_f32_16x16x32_bf16(a2, b0[2], acc0, 0, 0, 0);
        acc1 = __builtin_amdgcn_mfma_f32_16x16x32_bf16(a2, b1[2], acc1, 0, 0, 0);
        acc0 = __builtin_amdgcn_mfma_f32_16x16x32_bf16(a3, b0[3], acc0, 0, 0, 0);
        acc1 = __builtin_amdgcn_mfma_f32_16x16x32_bf16(a3, b1[3], acc1, 0, 0, 0);
        int row0 = rt * 16 + kg * 4;
        unsigned char* orow = outq + (size_t)row0 * 128 + wv * 32 + rlo;
#pragma unroll
        for (int r = 0; r < 4; ++r) {
            unsigned int pk = pk8x2(acc0[r], acc1[r]);
            orow[(size_t)r * 128] = (unsigned char)(pk & 0xFFu);
            orow[(size_t)r * 128 + 16] = (unsigned char)((pk >> 8) & 0xFFu);
        }
    }
}

// ---------- fused aggregate from fp8 hw; bf16 + fp8 + fp8(pw-scaled) outputs ----------
// one wave per dst row; 8 edges in flight (8-lane groups); 16B gathers of fp8 rows.
__global__ __launch_bounds__(256) void aggregate_kernel(
    const unsigned char* __restrict__ hwq, const int* __restrict__ rowptr,
    const int* __restrict__ csr_src, const float* __restrict__ dinv,
    const float* __restrict__ bias, const float* __restrict__ pwsl,
    ushort* __restrict__ zsl, unsigned char* __restrict__ zqsl,
    unsigned char* __restrict__ zqwsl, int n) {
    int gid = gtid();
    int row = gid >> 6;
    if (row >= n) return;
    int lane = threadIdx.x & 63;
    int g = lane >> 3;   // edge slot 0..7
    int c = lane & 7;    // feature chunk (16 feats)
    int j0 = rowptr[row], j1 = rowptr[row + 1];
    float dr = dinv[row];
    float acc[16];
#pragma unroll
    for (int k = 0; k < 16; ++k) acc[k] = 0.f;
    for (int j = j0 + g; j < j1; j += 8) {
        int s = csr_src[j];
        float cf = dinv[s] * dr;
        uint4 v = *reinterpret_cast<const uint4*>(hwq + (size_t)s * 128 + c * 16);
        float f[16];
        fp8x4_dec(v.x, f);
        fp8x4_dec(v.y, f + 4);
        fp8x4_dec(v.z, f + 8);
        fp8x4_dec(v.w, f + 12);
#pragma unroll
        for (int k = 0; k < 16; ++k) acc[k] = fmaf(cf, f[k], acc[k]);
    }
    // reduce across 8 edge slots
#pragma unroll
    for (int k = 0; k < 16; ++k) {
        acc[k] += __shfl_xor(acc[k], 8);
        acc[k] += __shfl_xor(acc[k], 16);
        acc[k] += __shfl_xor(acc[k], 32);
    }
    // self-loop + bias + relu
    float d2 = dr * dr;
    uint4 sv = *reinterpret_cast<const uint4*>(hwq + (size_t)row * 128 + c * 16);
    float sf[16];
    fp8x4_dec(sv.x, sf);
    fp8x4_dec(sv.y, sf + 4);
    fp8x4_dec(sv.z, sf + 8);
    fp8x4_dec(sv.w, sf + 12);
    float4 bb[4];
#pragma unroll
    for (int q = 0; q < 4; ++q)
        bb[q] = *reinterpret_cast<const float4*>(bias + c * 16 + q * 4);
    const float* bp = (const float*)bb;
#pragma unroll
    for (int k = 0; k < 16; ++k) {
        acc[k] = fmaxf(fmaf(d2, sf[k], acc[k]) + bp[k], 0.f);
    }

    if (g == 0) {
        // bf16 store: 16 feats = 32 B = 2x uint4
        unsigned int pk[8];
#pragma unroll
        for (int q = 0; q < 8; ++q) {
            pk[q] = (unsigned int)f2bfu(acc[2 * q]) | ((unsigned int)f2bfu(acc[2 * q + 1]) << 16);
        }
        ushort* zp = zsl + (size_t)row * 384 + c * 16;
        *reinterpret_cast<uint4*>(zp) = *reinterpret_cast<const uint4*>(pk);
        *reinterpret_cast<uint4*>(zp + 8) = *reinterpret_cast<const uint4*>(pk + 4);
    } else if (g == 1) {
        uint4 qq;
        qq.x = pk8x4(acc[0], acc[1], acc[2], acc[3]);
        qq.y = pk8x4(acc[4], acc[5], acc[6], acc[7]);
        qq.z = pk8x4(acc[8], acc[9], acc[10], acc[11]);
        qq.w = pk8x4(acc[12], acc[13], acc[14], acc[15]);
        *reinterpret_cast<uint4*>(zqsl + (size_t)row * 384 + c * 16) = qq;
    } else if (g == 2) {
        float w[16];
#pragma unroll
        for (int q = 0; q < 4; ++q) {
            float4 pv = *reinterpret_cast<const float4*>(pwsl + c * 16 + q * 4);
            const float* pp = (const float*)&pv;
#pragma unroll
            for (int t = 0; t < 4; ++t) w[q * 4 + t] = acc[q * 4 + t] * pp[t] * 8.0f;
        }
        uint4 ww;
        ww.x = pk8x4(w[0], w[1], w[2], w[3]);
        ww.y = pk8x4(w[4], w[5], w[6], w[7]);
        ww.z = pk8x4(w[8], w[9], w[10], w[11]);
        ww.w = pk8x4(w[12], w[13], w[14], w[15]);
        *reinterpret_cast<uint4*>(zqwsl + (size_t)row * 384 + c * 16) = ww;
    }
}

// ---------- loss: fp8 MFMA diagonal dot; 16 pairs per wave; partial per block ----------
__global__ __launch_bounds__(256) void loss_mfma_kernel(
    const unsigned char* __restrict__ zq, const unsigned char* __restrict__ zqw,
    const int* __restrict__ pos, const int* __restrict__ neg,
    const float* __restrict__ pb, float* __restrict__ partialOut,
    int p, float inv_total) {
    __shared__ float red[4];
    int lane = threadIdx.x & 63;
    int wv = threadIdx.x >> 6;
    int pairBase = (blockIdx.x * 4 + wv) * 16;
    float term = 0.f;
    if (pairBase < 2 * p) {
        int m = lane & 15;
        int kg = lane >> 4;
        int pi = pairBase + m;
        int pic = (pi < 2 * p) ? pi : (2 * p - 1);
        bool isneg = (pic >= p);
        const int* pr = isneg ? neg : pos;
        int idx = isneg ? (pic - p) : pic;
        int a = pr[idx];
        int b = pr[p + idx];
        const long* pa = reinterpret_cast<const long*>(zq + (size_t)a * 384) + kg;
        const long* pbw = reinterpret_cast<const long*>(zqw + (size_t)b * 384) + kg;
        long av[12], bv[12];
#pragma unroll
        for (int s = 0; s < 12; ++s) av[s] = pa[s * 4];
#pragma unroll
        for (int s = 0; s < 12; ++s) bv[s] = pbw[s * 4];
        f32x4 acc = {0.f, 0.f, 0.f, 0.f};
#pragma unroll
        for (int s = 0; s < 12; ++s) {
            acc = __builtin_amdgcn_mfma_f32_16x16x32_fp8_fp8(av[s], bv[s], acc, 0, 0, 0);
        }
        bool isdiag = (lane >> 4) == ((lane & 15) >> 2);
        int r2 = lane & 3;
        float v = (r2 == 0) ? acc[0] : (r2 == 1) ? acc[1] : (r2 == 2) ? acc[2] : acc[3];
        if (isdiag && pi < 2 * p) {
            float logit = v * 0.125f + pb[0];
            float t = isneg ? logit : -logit;
            term = (fmaxf(t, 0.f) + log1pf(expf(-fabsf(t)))) * inv_total;
        }
    }
#pragma unroll
    for (int off = 1; off < 64; off <<= 1) term += __shfl_xor(term, off);
    if (lane == 0) red[wv] = term;
    __syncthreads();
    if (threadIdx.x == 0) partialOut[blockIdx.x] = red[0] + red[1] + red[2] + red[3];
}

// single-block final reduction (no atomics)
__global__ __launch_bounds__(256) void loss_reduce_kernel(
    const float* __restrict__ partial, float* __restrict__ out, int m) {
    __shared__ float s[256];
    float a = 0.f;
    for (int i = threadIdx.x; i < m; i += 256) a += partial[i];
    s[threadIdx.x] = a;
    __syncthreads();
    for (int off = 128; off > 0; off >>= 1) {
        if (threadIdx.x < off) s[threadIdx.x] += s[threadIdx.x + off];
        __syncthreads();
    }
    if (threadIdx.x == 0) out[0] = s[0];
}

extern "C" void kernel_launch(void* const* d_in, const int* in_sizes, int n_in,
                              void* d_out, int out_size, void* d_ws, size_t ws_size,
                              hipStream_t stream) {
    const float* x      = (const float*)d_in[0];
    const int*   ei     = (const int*)d_in[1];
    const int*   pos    = (const int*)d_in[2];
    const int*   neg    = (const int*)d_in[3];
    const float* gcn_w  = (const float*)d_in[4];
    const float* gcn_b  = (const float*)d_in[5];
    const float* pred_w = (const float*)d_in[6];
    const float* pred_b = (const float*)d_in[7];
    float* out = (float*)d_out;

    const int n = in_sizes[0] / DD;     // 50000
    const int e = in_sizes[1] / 2;      // 640000
    const int p = in_sizes[2] / 2;      // 100000
    const int nb = (n + 255) / 256;

    char* ws = (char*)d_ws;
    size_t off = 0;
    auto alloc = [&](size_t bytes) {
        void* ptr = ws + off;
        off += (bytes + 255) & ~(size_t)255;
        return ptr;
    };
    float* dinv      = (float*)alloc((size_t)n * 4);
    int*   counts    = (int*)alloc((size_t)n * 4);
    int*   rowptr    = (int*)alloc((size_t)(n + 1) * 4);
    int*   cursor    = (int*)alloc((size_t)n * 4);
    int*   partial   = (int*)alloc(256 * 4);
    int*   partial2  = (int*)alloc(256 * 4);
    float* lossPart  = (float*)alloc((size_t)4096 * 4);
    int*   csr_src   = (int*)alloc((size_t)e * 4);
    ushort* wfrag    = (ushort*)alloc((size_t)3 * 2048 * 8 * 2);
    ushort* xh = (ushort*)alloc((size_t)n * 128 * 2);
    unsigned char* hwq = (unsigned char*)alloc((size_t)n * 128);
    ushort* zh = (ushort*)alloc((size_t)n * 384 * 2);
    unsigned char* zq  = (unsigned char*)alloc((size_t)n * 384);
    unsigned char* zqw = (unsigned char*)alloc((size_t)n * 384);
    (void)ws_size;

    hipMemsetAsync(counts, 0, (size_t)n * 4, stream);
    hipMemsetAsync(d_out, 0, (size_t)out_size * 4, stream);

    count_kernel<<<(e + 255) / 256, 256, 0, stream>>>(counts, ei + e, e);
    dinv_kernel<<<nb, 256, 0, stream>>>(dinv, counts, n);
    scan_blocks<<<nb, 256, 0, stream>>>(counts, rowptr, partial, n);
    scan_partials<<<1, 256, 0, stream>>>(partial, partial2, nb);
    add_offsets<<<nb, 256, 0, stream>>>(rowptr, cursor, partial2, n, e);
    fill_kernel<<<(e + 255) / 256, 256, 0, stream>>>(ei, cursor, csr_src, e);

    cvt_kernel<<<(int)(((size_t)n * 128 + 255) / 256), 256, 0, stream>>>(
        x, (__hip_bfloat16*)xh, (size_t)n * 128);
    wpack_kernel<<<24, 256, 0, stream>>>(gcn_w, wfrag);

    const int ntiles = n / 16;
    const int aggBlocks = (n * 64 + 255) / 256;
    for (int l = 0; l < 3; ++l) {
        const ushort* hsrc = (l == 0) ? xh : (zh + (size_t)(l - 1) * 128);
        int ld = (l == 0) ? 128 : 384;
        gemm_mfma_kernel<<<ntiles, 256, 0, stream>>>(
            hsrc, ld, wfrag + (size_t)l * 2048 * 8, hwq, ntiles);
        aggregate_kernel<<<aggBlocks, 256, 0, stream>>>(
            hwq, rowptr, csr_src, dinv, gcn_b + (size_t)l * 128,
            pred_w + (size_t)l * 128,
            zh + (size_t)l * 128, zq + (size_t)l * 128, zqw + (size_t)l * 128, n);
    }

    float inv_total = 1.0f / (2.0f * (float)p);
    int lossBlocks = (2 * p + 63) / 64;  // 3125
    loss_mfma_kernel<<<lossBlocks, 256, 0, stream>>>(
        zq, zqw, pos, neg, pred_b, lossPart, p, inv_total);
    loss_reduce_kernel<<<1, 256, 0, stream>>>(lossPart, out, lossBlocks);
}

// Round 12
// 285.698 us; speedup vs baseline: 1.6705x; 1.0087x over previous
//
#include <hip/hip_runtime.h>
#include <hip/hip_bf16.h>

#define DD 128

typedef __attribute__((ext_vector_type(8))) short short8;
typedef __attribute__((ext_vector_type(4))) float f32x4;
typedef __attribute__((ext_vector_type(2))) float f32x2;

static __device__ __forceinline__ int gtid() {
    return blockIdx.x * blockDim.x + threadIdx.x;
}

static __device__ __forceinline__ ushort f2bfu(float f) {
    __hip_bfloat16 h = __float2bfloat16(f);
    return *reinterpret_cast<ushort*>(&h);
}

// ---- fp8 e4m3fn encode/decode (manual fallback, RNE, subnormal-correct) ----
static __device__ __forceinline__ unsigned int fp8e(float f) {
    unsigned int s = (__float_as_uint(f) >> 31) << 7;
    float a = fabsf(f);
    if (a < 0.015625f) return s | (unsigned int)rintf(a * 512.0f);
    unsigned int u = __float_as_uint(a);
    u += 0x0007FFFFu + ((u >> 20) & 1u);
    unsigned int e8 = (u >> 23) - 120u;
    unsigned int m = (u >> 20) & 7u;
    if (e8 > 15u || (e8 == 15u && m == 7u)) return s | 0x7Eu;
    return s | (e8 << 3) | m;
}

static __device__ __forceinline__ float fp8d(unsigned int b) {
    unsigned int t = b & 0x7Fu;
    float v = (t >= 8u) ? __uint_as_float((t << 20) + 0x3C000000u)
                        : (float)t * 0.001953125f;
    return (b & 0x80u) ? -v : v;
}

static __device__ __forceinline__ unsigned int pk8x4(float a, float b, float c, float d) {
#if __has_builtin(__builtin_amdgcn_cvt_pk_fp8_f32)
    int v = __builtin_amdgcn_cvt_pk_fp8_f32(a, b, 0, false);
    v = __builtin_amdgcn_cvt_pk_fp8_f32(c, d, v, true);
    return (unsigned int)v;
#else
    return fp8e(a) | (fp8e(b) << 8) | (fp8e(c) << 16) | (fp8e(d) << 24);
#endif
}

static __device__ __forceinline__ unsigned int pk8x2(float a, float b) {
#if __has_builtin(__builtin_amdgcn_cvt_pk_fp8_f32)
    return (unsigned int)__builtin_amdgcn_cvt_pk_fp8_f32(a, b, 0, false);
#else
    return fp8e(a) | (fp8e(b) << 8);
#endif
}

static __device__ __forceinline__ void fp8x4_dec(unsigned int u, float* f) {
#if __has_builtin(__builtin_amdgcn_cvt_pk_f32_fp8)
    f32x2 lo = __builtin_amdgcn_cvt_pk_f32_fp8((int)u, false);
    f32x2 hi = __builtin_amdgcn_cvt_pk_f32_fp8((int)u, true);
    f[0] = lo[0]; f[1] = lo[1]; f[2] = hi[0]; f[3] = hi[1];
#else
    f[0] = fp8d(u & 0xFFu);
    f[1] = fp8d((u >> 8) & 0xFFu);
    f[2] = fp8d((u >> 16) & 0xFFu);
    f[3] = fp8d((u >> 24) & 0xFFu);
#endif
}

// ---------- degree / CSR build ----------

__global__ void count_kernel(int* __restrict__ counts, const int* __restrict__ dst, int e) {
    int i = gtid();
    if (i < e) atomicAdd(&counts[dst[i]], 1);
}

__global__ void dinv_kernel(float* __restrict__ dinv, const int* __restrict__ counts, int n) {
    int i = gtid();
    if (i < n) dinv[i] = rsqrtf(1.0f + (float)counts[i]);
}

__global__ __launch_bounds__(256) void scan_blocks(const int* __restrict__ counts,
                                                   int* __restrict__ rowptr,
                                                   int* __restrict__ partial, int n) {
    __shared__ int s[256];
    int i = blockIdx.x * 256 + threadIdx.x;
    int v = (i < n) ? counts[i] : 0;
    s[threadIdx.x] = v;
    __syncthreads();
    for (int off = 1; off < 256; off <<= 1) {
        int t = (threadIdx.x >= off) ? s[threadIdx.x - off] : 0;
        __syncthreads();
        s[threadIdx.x] += t;
        __syncthreads();
    }
    if (i < n) rowptr[i] = s[threadIdx.x] - v;
    if (threadIdx.x == 255) partial[blockIdx.x] = s[255];
}

__global__ __launch_bounds__(256) void scan_partials(int* __restrict__ partial,
                                                     int* __restrict__ partial2, int nb) {
    __shared__ int s[256];
    int v = (threadIdx.x < nb) ? partial[threadIdx.x] : 0;
    s[threadIdx.x] = v;
    __syncthreads();
    for (int off = 1; off < 256; off <<= 1) {
        int t = (threadIdx.x >= off) ? s[threadIdx.x - off] : 0;
        __syncthreads();
        s[threadIdx.x] += t;
        __syncthreads();
    }
    partial2[threadIdx.x] = s[threadIdx.x] - v;
}

__global__ __launch_bounds__(256) void add_offsets(int* __restrict__ rowptr,
                                                   int* __restrict__ cursor,
                                                   const int* __restrict__ partial2,
                                                   int n, int e) {
    int i = blockIdx.x * 256 + threadIdx.x;
    if (i < n) {
        int r = rowptr[i] + partial2[blockIdx.x];
        rowptr[i] = r;
        cursor[i] = r;
        if (i == n - 1) rowptr[n] = e;
    }
}

__global__ void fill_kernel(const int* __restrict__ ei, int* __restrict__ cursor,
                            int* __restrict__ csr_src, int e) {
    int i = gtid();
    if (i >= e) return;
    int s = ei[i];
    int d = ei[e + i];
    int pos = atomicAdd(&cursor[d], 1);
    __builtin_nontemporal_store(s, &csr_src[pos]);
}

// ---------- x -> bf16 ----------
__global__ void cvt_kernel(const float* __restrict__ x, __hip_bfloat16* __restrict__ xh, size_t m) {
    size_t i = (size_t)blockIdx.x * blockDim.x + threadIdx.x;
    if (i < m) xh[i] = __float2bfloat16(x[i]);
}

// ---------- W -> bf16 MFMA B-fragment order ----------
__global__ __launch_bounds__(256) void wpack_kernel(const float* __restrict__ gcn_w,
                                                    ushort* __restrict__ wfrag) {
    int tid = blockIdx.x * 256 + threadIdx.x;
    if (tid >= 3 * 4 * 8 * 64) return;
    int lane = tid & 63;
    int c = (tid >> 6) & 7;
    int s = (tid >> 9) & 3;
    int l = tid >> 11;
    const float* W = gcn_w + (size_t)l * 128 * 128;
    int col = c * 16 + (lane & 15);
    int k0 = s * 32 + (lane >> 4) * 8;
    ushort u[8];
#pragma unroll
    for (int j = 0; j < 8; ++j) {
        u[j] = f2bfu(W[(size_t)(k0 + j) * 128 + col]);
    }
    *reinterpret_cast<uint4*>(wfrag + (size_t)tid * 8) = *reinterpret_cast<const uint4*>(u);
}

// ---------- aggregate-first: aggh[row,:] = sum coef*src_row + d2*self (NO bias/relu) ----------
// 4 edge slots (g=lane>>4) x 16 feature chunks (c=lane&15, 8 feats each).

// layer-0 variant: bf16 source, dense [n][128]
__global__ __launch_bounds__(256) void aggregate_bf16_kernel(
    const ushort* __restrict__ src, const int* __restrict__ rowptr,
    const int* __restrict__ csr_src, const float* __restrict__ dinv,
    ushort* __restrict__ aggh, int n) {
    int gid = gtid();
    int row = gid >> 6;
    if (row >= n) return;
    int lane = threadIdx.x & 63;
    int g = lane >> 4;
    int c = lane & 15;
    int j0 = rowptr[row], j1 = rowptr[row + 1];
    float dr = dinv[row];
    float acc[8] = {0.f, 0.f, 0.f, 0.f, 0.f, 0.f, 0.f, 0.f};
    for (int j = j0 + g; j < j1; j += 4) {
        int s = csr_src[j];
        float cf = dinv[s] * dr;
        uint4 v = *reinterpret_cast<const uint4*>(src + (size_t)s * 128 + c * 8);
        const unsigned int* u = (const unsigned int*)&v;
#pragma unroll
        for (int q = 0; q < 4; ++q) {
            acc[2 * q] = fmaf(cf, __uint_as_float(u[q] << 16), acc[2 * q]);
            acc[2 * q + 1] = fmaf(cf, __uint_as_float(u[q] & 0xffff0000u), acc[2 * q + 1]);
        }
    }
#pragma unroll
    for (int k = 0; k < 8; ++k) {
        acc[k] += __shfl_xor(acc[k], 16);
        acc[k] += __shfl_xor(acc[k], 32);
    }
    // self-loop (all lanes hold total now)
    float d2 = dr * dr;
    uint4 sv = *reinterpret_cast<const uint4*>(src + (size_t)row * 128 + c * 8);
    const unsigned int* su = (const unsigned int*)&sv;
#pragma unroll
    for (int q = 0; q < 4; ++q) {
        acc[2 * q] = fmaf(d2, __uint_as_float(su[q] << 16), acc[2 * q]);
        acc[2 * q + 1] = fmaf(d2, __uint_as_float(su[q] & 0xffff0000u), acc[2 * q + 1]);
    }
    if (g == 0) {
        unsigned int pk[4];
#pragma unroll
        for (int q = 0; q < 4; ++q) {
            pk[q] = (unsigned int)f2bfu(acc[2 * q]) | ((unsigned int)f2bfu(acc[2 * q + 1]) << 16);
        }
        *reinterpret_cast<uint4*>(aggh + (size_t)row * 128 + c * 8) =
            *reinterpret_cast<const uint4*>(pk);
    }
}

// layer>=1 variant: fp8 source slice of zq (row stride 384)
__global__ __launch_bounds__(256) void aggregate_fp8_kernel(
    const unsigned char* __restrict__ srcq, const int* __restrict__ rowptr,
    const int* __restrict__ csr_src, const float* __restrict__ dinv,
    ushort* __restrict__ aggh, int n) {
    int gid = gtid();
    int row = gid >> 6;
    if (row >= n) return;
    int lane = threadIdx.x & 63;
    int g = lane >> 4;
    int c = lane & 15;
    int j0 = rowptr[row], j1 = rowptr[row + 1];
    float dr = dinv[row];
    float acc[8] = {0.f, 0.f, 0.f, 0.f, 0.f, 0.f, 0.f, 0.f};
    for (int j = j0 + g; j < j1; j += 4) {
        int s = csr_src[j];
        float cf = dinv[s] * dr;
        uint2 v = *reinterpret_cast<const uint2*>(srcq + (size_t)s * 384 + c * 8);
        float f[8];
        fp8x4_dec(v.x, f);
        fp8x4_dec(v.y, f + 4);
#pragma unroll
        for (int k = 0; k < 8; ++k) acc[k] = fmaf(cf, f[k], acc[k]);
    }
#pragma unroll
    for (int k = 0; k < 8; ++k) {
        acc[k] += __shfl_xor(acc[k], 16);
        acc[k] += __shfl_xor(acc[k], 32);
    }
    float d2 = dr * dr;
    uint2 sv = *reinterpret_cast<const uint2*>(srcq + (size_t)row * 384 + c * 8);
    float sf[8];
    fp8x4_dec(sv.x, sf);
    fp8x4_dec(sv.y, sf + 4);
#pragma unroll
    for (int k = 0; k < 8; ++k) acc[k] = fmaf(d2, sf[k], acc[k]);
    if (g == 0) {
        unsigned int pk[4];
#pragma unroll
        for (int q = 0; q < 4; ++q) {
            pk[q] = (unsigned int)f2bfu(acc[2 * q]) | ((unsigned int)f2bfu(acc[2 * q + 1]) << 16);
        }
        *reinterpret_cast<uint4*>(aggh + (size_t)row * 128 + c * 8) =
            *reinterpret_cast<const uint4*>(pk);
    }
}

// ---------- MFMA GEMM: aggh @ W + bias -> relu -> zq (fp8) + zqw (fp8*pw*8) slices ----------
__global__ __launch_bounds__(256) void gemm_mfma_kernel(
    const ushort* __restrict__ aggh, const ushort* __restrict__ wfrag,
    const float* __restrict__ bias, const float* __restrict__ pwsl,
    unsigned char* __restrict__ zq_sl, unsigned char* __restrict__ zqw_sl, int ntiles) {
    int lane = threadIdx.x & 63;
    int wv = threadIdx.x >> 6;
    short8 b0[4], b1[4];
    int c0 = wv * 2;
#pragma unroll
    for (int s = 0; s < 4; ++s) {
        b0[s] = *reinterpret_cast<const short8*>(wfrag + ((size_t)(s * 8 + c0) * 64 + lane) * 8);
        b1[s] = *reinterpret_cast<const short8*>(wfrag + ((size_t)(s * 8 + c0 + 1) * 64 + lane) * 8);
    }
    int rlo = lane & 15;
    int kg = lane >> 4;
    int col0 = wv * 32 + rlo;
    int col1 = col0 + 16;
    float bias0 = bias[col0], bias1 = bias[col1];
    float pw0 = pwsl[col0] * 8.0f, pw1 = pwsl[col1] * 8.0f;
    for (int rt = blockIdx.x; rt < ntiles; rt += gridDim.x) {
        const ushort* ap = aggh + (size_t)(rt * 16 + rlo) * 128 + kg * 8;
        short8 a0 = *reinterpret_cast<const short8*>(ap);
        short8 a1 = *reinterpret_cast<const short8*>(ap + 32);
        short8 a2 = *reinterpret_cast<const short8*>(ap + 64);
        short8 a3 = *reinterpret_cast<const short8*>(ap + 96);
        f32x4 acc0 = {0.f, 0.f, 0.f, 0.f};
        f32x4 acc1 = {0.f, 0.f, 0.f, 0.f};
        acc0 = __builtin_amdgcn_mfma_f32_16x16x32_bf16(a0, b0[0], acc0, 0, 0, 0);
        acc1 = __builtin_amdgcn_mfma_f32_16x16x32_bf16(a0, b1[0], acc1, 0, 0, 0);
        acc0 = __builtin_amdgcn_mfma_f32_16x16x32_bf16(a1, b0[1], acc0, 0, 0, 0);
        acc1 = __builtin_amdgcn_mfma_f32_16x16x32_bf16(a1, b1[1], acc1, 0, 0, 0);
        acc0 = __builtin_amdgcn_mfma_f32_16x16x32_bf16(a2, b0[2], acc0, 0, 0, 0);
        acc1 = __builtin_amdgcn_mfma_f32_16x16x32_bf16(a2, b1[2], acc1, 0, 0, 0);
        acc0 = __builtin_amdgcn_mfma_f32_16x16x32_bf16(a3, b0[3], acc0, 0, 0, 0);
        acc1 = __builtin_amdgcn_mfma_f32_16x16x32_bf16(a3, b1[3], acc1, 0, 0, 0);
        int row0 = rt * 16 + kg * 4;
#pragma unroll
        for (int r = 0; r < 4; ++r) {
            float v0 = fmaxf(acc0[r] + bias0, 0.f);
            float v1 = fmaxf(acc1[r] + bias1, 0.f);
            unsigned int q = pk8x2(v0, v1);
            unsigned char* zr = zq_sl + (size_t)(row0 + r) * 384 + col0;
            zr[0] = (unsigned char)(q & 0xFFu);
            zr[16] = (unsigned char)((q >> 8) & 0xFFu);
            unsigned int w = pk8x2(v0 * pw0, v1 * pw1);
            unsigned char* wr = zqw_sl + (size_t)(row0 + r) * 384 + col0;
            wr[0] = (unsigned char)(w & 0xFFu);
            wr[16] = (unsigned char)((w >> 8) & 0xFFu);
        }
    }
}

// ---------- loss: fp8 MFMA diagonal dot; 16 pairs per wave; partial per block ----------
__global__ __launch_bounds__(256) void loss_mfma_kernel(
    const unsigned char* __restrict__ zq, const unsigned char* __restrict__ zqw,
    const int* __restrict__ pos, const int* __restrict__ neg,
    const float* __restrict__ pb, float* __restrict__ partialOut,
    int p, float inv_total) {
    __shared__ float red[4];
    int lane = threadIdx.x & 63;
    int wv = threadIdx.x >> 6;
    int pairBase = (blockIdx.x * 4 + wv) * 16;
    float term = 0.f;
    if (pairBase < 2 * p) {
        int m = lane & 15;
        int kg = lane >> 4;
        int pi = pairBase + m;
        int pic = (pi < 2 * p) ? pi : (2 * p - 1);
        bool isneg = (pic >= p);
        const int* pr = isneg ? neg : pos;
        int idx = isneg ? (pic - p) : pic;
        int a = pr[idx];
        int b = pr[p + idx];
        const long* pa = reinterpret_cast<const long*>(zq + (size_t)a * 384) + kg;
        const long* pbw = reinterpret_cast<const long*>(zqw + (size_t)b * 384) + kg;
        long av[12], bv[12];
#pragma unroll
        for (int s = 0; s < 12; ++s) av[s] = pa[s * 4];
#pragma unroll
        for (int s = 0; s < 12; ++s) bv[s] = pbw[s * 4];
        f32x4 acc = {0.f, 0.f, 0.f, 0.f};
#pragma unroll
        for (int s = 0; s < 12; ++s) {
            acc = __builtin_amdgcn_mfma_f32_16x16x32_fp8_fp8(av[s], bv[s], acc, 0, 0, 0);
        }
        bool isdiag = (lane >> 4) == ((lane & 15) >> 2);
        int r2 = lane & 3;
        float v = (r2 == 0) ? acc[0] : (r2 == 1) ? acc[1] : (r2 == 2) ? acc[2] : acc[3];
        if (isdiag && pi < 2 * p) {
            float logit = v * 0.125f + pb[0];
            float t = isneg ? logit : -logit;
            term = (fmaxf(t, 0.f) + log1pf(expf(-fabsf(t)))) * inv_total;
        }
    }
#pragma unroll
    for (int off = 1; off < 64; off <<= 1) term += __shfl_xor(term, off);
    if (lane == 0) red[wv] = term;
    __syncthreads();
    if (threadIdx.x == 0) partialOut[blockIdx.x] = red[0] + red[1] + red[2] + red[3];
}

__global__ __launch_bounds__(256) void loss_reduce_kernel(
    const float* __restrict__ partial, float* __restrict__ out, int m) {
    __shared__ float s[256];
    float a = 0.f;
    for (int i = threadIdx.x; i < m; i += 256) a += partial[i];
    s[threadIdx.x] = a;
    __syncthreads();
    for (int off = 128; off > 0; off >>= 1) {
        if (threadIdx.x < off) s[threadIdx.x] += s[threadIdx.x + off];
        __syncthreads();
    }
    if (threadIdx.x == 0) out[0] = s[0];
}

extern "C" void kernel_launch(void* const* d_in, const int* in_sizes, int n_in,
                              void* d_out, int out_size, void* d_ws, size_t ws_size,
                              hipStream_t stream) {
    const float* x      = (const float*)d_in[0];
    const int*   ei     = (const int*)d_in[1];
    const int*   pos    = (const int*)d_in[2];
    const int*   neg    = (const int*)d_in[3];
    const float* gcn_w  = (const float*)d_in[4];
    const float* gcn_b  = (const float*)d_in[5];
    const float* pred_w = (const float*)d_in[6];
    const float* pred_b = (const float*)d_in[7];
    float* out = (float*)d_out;

    const int n = in_sizes[0] / DD;     // 50000
    const int e = in_sizes[1] / 2;      // 640000
    const int p = in_sizes[2] / 2;      // 100000
    const int nb = (n + 255) / 256;

    char* ws = (char*)d_ws;
    size_t off = 0;
    auto alloc = [&](size_t bytes) {
        void* ptr = ws + off;
        off += (bytes + 255) & ~(size_t)255;
        return ptr;
    };
    float* dinv      = (float*)alloc((size_t)n * 4);
    int*   counts    = (int*)alloc((size_t)n * 4);
    int*   rowptr    = (int*)alloc((size_t)(n + 1) * 4);
    int*   cursor    = (int*)alloc((size_t)n * 4);
    int*   partial   = (int*)alloc(256 * 4);
    int*   partial2  = (int*)alloc(256 * 4);
    float* lossPart  = (float*)alloc((size_t)4096 * 4);
    int*   csr_src   = (int*)alloc((size_t)e * 4);
    ushort* wfrag    = (ushort*)alloc((size_t)3 * 2048 * 8 * 2);
    ushort* xh   = (ushort*)alloc((size_t)n * 128 * 2);
    ushort* aggh = (ushort*)alloc((size_t)n * 128 * 2);
    unsigned char* zq  = (unsigned char*)alloc((size_t)n * 384);
    unsigned char* zqw = (unsigned char*)alloc((size_t)n * 384);
    (void)ws_size;

    hipMemsetAsync(counts, 0, (size_t)n * 4, stream);

    count_kernel<<<(e + 255) / 256, 256, 0, stream>>>(counts, ei + e, e);
    dinv_kernel<<<nb, 256, 0, stream>>>(dinv, counts, n);
    scan_blocks<<<nb, 256, 0, stream>>>(counts, rowptr, partial, n);
    scan_partials<<<1, 256, 0, stream>>>(partial, partial2, nb);
    add_offsets<<<nb, 256, 0, stream>>>(rowptr, cursor, partial2, n, e);
    fill_kernel<<<(e + 255) / 256, 256, 0, stream>>>(ei, cursor, csr_src, e);

    cvt_kernel<<<(int)(((size_t)n * 128 + 255) / 256), 256, 0, stream>>>(
        x, (__hip_bfloat16*)xh, (size_t)n * 128);
    wpack_kernel<<<24, 256, 0, stream>>>(gcn_w, wfrag);

    const int ntiles = n / 16;
    const int aggBlocks = (n * 64 + 255) / 256;
    for (int l = 0; l < 3; ++l) {
        if (l == 0) {
            aggregate_bf16_kernel<<<aggBlocks, 256, 0, stream>>>(
                xh, rowptr, csr_src, dinv, aggh, n);
        } else {
            aggregate_fp8_kernel<<<aggBlocks, 256, 0, stream>>>(
                zq + (size_t)(l - 1) * 128, rowptr, csr_src, dinv, aggh, n);
        }
        gemm_mfma_kernel<<<ntiles, 256, 0, stream>>>(
            aggh, wfrag + (size_t)l * 2048 * 8,
            gcn_b + (size_t)l * 128, pred_w + (size_t)l * 128,
            zq + (size_t)l * 128, zqw + (size_t)l * 128, ntiles);
    }

    float inv_total = 1.0f / (2.0f * (float)p);
    int lossBlocks = (2 * p + 63) / 64;  // 3125
    loss_mfma_kernel<<<lossBlocks, 256, 0, stream>>>(
        zq, zqw, pos, neg, pred_b, lossPart, p, inv_total);
    loss_reduce_kernel<<<1, 256, 0, stream>>>(lossPart, out, lossBlocks);
}